// Round 9
// baseline (408.531 us; speedup 1.0000x reference)
//
#include <hip/hip_runtime.h>

#define HH 51
#define TT 256
#define NB 16
#define L2E 1.442695041f

typedef __attribute__((ext_vector_type(8))) __bf16 bf16x8;
typedef __attribute__((ext_vector_type(4))) float  floatx4;

#define MFMA16(A,B,C) __builtin_amdgcn_mfma_f32_16x16x32_bf16((A),(B),(C),0,0,0)

__device__ __forceinline__ float rcp_fast(float x) { return __builtin_amdgcn_rcpf(x); }
#if __has_builtin(__builtin_amdgcn_exp2f)
__device__ __forceinline__ float exp2_fast(float x) { return __builtin_amdgcn_exp2f(x); }
#else
__device__ __forceinline__ float exp2_fast(float x) { return __expf(0.69314718056f * x); }
#endif
__device__ __forceinline__ unsigned short f2bf(float f) {
    unsigned u = __float_as_uint(f);
    unsigned r = (u + 0x7FFFu + ((u >> 16) & 1u)) >> 16;
    return (unsigned short)r;
}
__device__ __forceinline__ float bf2f(unsigned short h) {
    return __uint_as_float(((unsigned)h) << 16);
}

// ------------- weight pre-pack: rounds-4..8 layout + bias/x K-columns ----
// B-frag 16x16x32: lane holds B[k=(lane>>4)*8+jj][n=lane&15].
// ids: cell1 ((g*4+U)*2+s)*2+hl (64) | cell2 64+((g*4+U)*4+s)*2+hl (128) |
//      head 192+s*2+hl (4). ws = 196*64*16 B.
// K-columns: cell1 k<51=Whh1, k=51=bih1+bhh1, k=52=Wih1 (pairs with h1[52]=x).
//            cell2 h1-half k<51=Wih2, k=51=bih2+bhh2; h2-half k2<51=Whh2.
//            head n=0: k<51=Wlin, k=51=blin (pairs with h2[51]=1.0).
// Gate scales folded: i,f,o *L2E ; g *2*L2E ; head unscaled.
__global__ void lstm_prep(const float* __restrict__ Whh1, const float* __restrict__ Wih1,
                          const float* __restrict__ bih1, const float* __restrict__ bhh1,
                          const float* __restrict__ Wih2, const float* __restrict__ Whh2,
                          const float* __restrict__ bih2, const float* __restrict__ bhh2,
                          const float* __restrict__ Wlin, const float* __restrict__ blin,
                          uint4* __restrict__ frags) {
    int tid = blockIdx.x * blockDim.x + threadIdx.x;
    if (tid >= 196 * 64) return;
    int f = tid >> 6, lane = tid & 63;
    int n = lane & 15, qq = lane >> 4;
    int hl, s, tau, cell;
    if (f < 64)       { cell = 1; int r = f;       hl = r & 1; r >>= 1; s = r & 1; tau = r >> 1; }
    else if (f < 192) { cell = 2; int r = f - 64;  hl = r & 1; r >>= 1; s = r & 3; tau = r >> 2; }
    else              { cell = 3; int r = f - 192; hl = r & 1; s = r >> 1; tau = 0; }
    int g = tau >> 2, U = tau & 3, u = U * 16 + n;
    float sc = (cell == 3) ? 1.0f : ((g == 2) ? 2.0f * L2E : L2E);
    unsigned int dw[4];
    for (int d = 0; d < 4; d++) {
        unsigned int packed = 0;
        for (int e = 0; e < 2; e++) {
            int jj = d * 2 + e;
            int k = s * 32 + qq * 8 + jj;
            float val = 0.f;
            if (cell == 1) {
                if (u < HH) {
                    if (k < HH)       val = Whh1[(g * HH + u) * HH + k];
                    else if (k == 51) val = bih1[g * HH + u] + bhh1[g * HH + u];
                    else if (k == 52) val = Wih1[g * HH + u];
                }
            } else if (cell == 2) {
                if (u < HH) {
                    if (k < 64) {
                        if (k < HH)       val = Wih2[(g * HH + u) * HH + k];
                        else if (k == 51) val = bih2[g * HH + u] + bhh2[g * HH + u];
                    } else {
                        int k2 = k - 64;
                        if (k2 < HH) val = Whh2[(g * HH + u) * HH + k2];
                    }
                }
            } else {
                if (n == 0) {
                    if (k < HH)       val = Wlin[k];
                    else if (k == 51) val = blin[0];
                }
            }
            val *= sc;
            unsigned short hi = f2bf(val);
            unsigned short bits = hl ? f2bf(val - bf2f(hi)) : hi;
            packed |= ((unsigned int)bits) << (16 * e);
        }
        dw[d] = packed;
    }
    frags[f * 64 + lane] = make_uint4(dw[0], dw[1], dw[2], dw[3]);
}

// -------------------------------------------------------------------------
// One-barrier skewed LSTM (round-7/8 structure), VALU-minimized:
//  - zero-C MFMA init (bias/x live in K-columns 51/52 of the h vectors)
//  - peeled last k-step per gate: exp2+rcp tails overlap later gates' MFMAs
//  - c kept scaled by 2*log2(e); head rotated across c1 waves
// h layout/swizzle identical to rounds 7/8 (verified):
//   write wi = (((u>>1)+4*(b>>1))&31)*2 + (u&1) ; read base per k-step.
// h1[b][51]=1.0 (bias hook), h1[b][52]=x(t+1) written in ACT; h2[b][51]=1.0
// (head-bias hook). Pad u>=53 stays 0.
// -------------------------------------------------------------------------
__launch_bounds__(512, 2)
__global__ void lstm_main(const float* __restrict__ input,
                          const uint4* __restrict__ frags,
                          float* __restrict__ out) {
    __shared__ __align__(16) unsigned int h1h[2][16][36], h1l[2][16][36];
    __shared__ __align__(16) unsigned int h2h[2][16][36], h2l[2][16][36];
    __shared__ __align__(16) float xb[(TT + 1) * 16];    // [t][b], row TT = 0

    const int tid  = threadIdx.x;
    const int lane = tid & 63;
    const int w    = tid >> 6;
    const int l15  = lane & 15;
    const int q    = lane >> 4;
    const int b0g  = blockIdx.x * NB;
    const bool c2w = (w < 4);
    const int U    = c2w ? w : (w - 4);
    const int uc   = U * 16 + l15;
    const bool uok = (uc < HH);

    for (int i = tid; i < 2 * 16 * 36; i += 512) {
        ((unsigned*)h1h)[i] = 0; ((unsigned*)h1l)[i] = 0;
        ((unsigned*)h2h)[i] = 0; ((unsigned*)h2l)[i] = 0;
    }
    for (int c = 0; c < 2; c++) {
        int flat = tid + c * 512;
        int b = flat >> 6, t0 = (flat & 63) * 4;
        float4 v = *(const float4*)&input[(size_t)(b0g + b) * TT + t0];
        xb[(t0 + 0) * 16 + b] = v.x; xb[(t0 + 1) * 16 + b] = v.y;
        xb[(t0 + 2) * 16 + b] = v.z; xb[(t0 + 3) * 16 + b] = v.w;
    }
    if (tid < 16) xb[TT * 16 + tid] = 0.f;
    __syncthreads();                    // zero-init done before targeted pokes
    if (tid < 16) {
        int b = tid;
        int wi51 = ((25 + 4 * (b >> 1)) & 31) * 2 + 1;   // u=51
        int wi52 = ((26 + 4 * (b >> 1)) & 31) * 2 + 0;   // u=52
        unsigned short one = 0x3F80;                     // bf16(1.0)
        ((unsigned short*)&h1h[0][b][0])[wi51] = one;
        ((unsigned short*)&h1h[1][b][0])[wi51] = one;
        ((unsigned short*)&h2h[0][b][0])[wi51] = one;
        ((unsigned short*)&h2h[1][b][0])[wi51] = one;
        float x0 = input[(size_t)(b0g + b) * TT];        // x(0) -> h1[par1][52]
        unsigned hb = __float_as_uint(x0);
        ((unsigned short*)&h1h[1][b][0])[wi52] = (unsigned short)(hb >> 16);
        float lof = x0 - __uint_as_float(hb & 0xFFFF0000u);
        ((unsigned short*)&h1l[1][b][0])[wi52] = (unsigned short)(__float_as_uint(lof) >> 16);
    }

    // weight-stationary fragments
    bf16x8 fr[32];
    if (c2w) {
#pragma unroll
        for (int g = 0; g < 4; g++) {
            int tau = g * 4 + U;
#pragma unroll
            for (int s = 0; s < 4; s++) {
                fr[g * 8 + s * 2 + 0] = __builtin_bit_cast(bf16x8, frags[(64 + (tau * 4 + s) * 2 + 0) * 64 + lane]);
                fr[g * 8 + s * 2 + 1] = __builtin_bit_cast(bf16x8, frags[(64 + (tau * 4 + s) * 2 + 1) * 64 + lane]);
            }
        }
    } else {
#pragma unroll
        for (int g = 0; g < 4; g++) {
            int tau = g * 4 + U;
#pragma unroll
            for (int s = 0; s < 2; s++) {
                fr[g * 4 + s * 2 + 0] = __builtin_bit_cast(bf16x8, frags[((tau * 2 + s) * 2 + 0) * 64 + lane]);
                fr[g * 4 + s * 2 + 1] = __builtin_bit_cast(bf16x8, frags[((tau * 2 + s) * 2 + 1) * 64 + lane]);
            }
        }
#pragma unroll
        for (int s = 0; s < 2; s++) {   // head frags on ALL c1 waves (rotation)
            fr[16 + s * 2 + 0] = __builtin_bit_cast(bf16x8, frags[(192 + s * 2 + 0) * 64 + lane]);
            fr[16 + s * 2 + 1] = __builtin_bit_cast(bf16x8, frags[(192 + s * 2 + 1) * 64 + lane]);
        }
    }
    floatx4 zacc = {0.f, 0.f, 0.f, 0.f};
    float cst[4] = {0.f, 0.f, 0.f, 0.f};
    const int baseA = (q * 4 + 4 * (l15 >> 1)) & 31;
    const int baseB = (baseA + 16) & 31;

    __syncthreads();

// per-gate trans tail: f = rcp(1 + exp2(sign * d))
#define GTAIL(DG, FG, SGN)                                                      \
    _Pragma("unroll")                                                           \
    for (int r = 0; r < 4; r++) {                                               \
        float e = exp2_fast(SGN (DG)[r]);                                       \
        (FG)[r] = rcp_fast(1.0f + e);                                           \
    }

#define FIN_SPLIT(HV, DSTH, DSTL, PW)                                           \
    do {                                                                        \
        unsigned hb_ = __float_as_uint(HV);                                     \
        unsigned short hi_ = (unsigned short)(hb_ >> 16);                       \
        float lo_f = (HV) - __uint_as_float(hb_ & 0xFFFF0000u);                 \
        unsigned short lo_ = (unsigned short)(__float_as_uint(lo_f) >> 16);     \
        int bb_ = q * 4 + r;                                                    \
        int wi_ = (((uc >> 1) + 4 * (bb_ >> 1)) & 31) * 2 + (uc & 1);           \
        ((unsigned short*)&DSTH[PW][bb_][0])[wi_] = hi_;                        \
        ((unsigned short*)&DSTL[PW][bb_][0])[wi_] = lo_;                        \
    } while (0)

#define STEP(IT, P)                                                             \
    do {                                                                        \
        if (c2w) {                                                              \
            if ((IT) >= 1 && (IT) <= TT) {                                      \
                floatx4 d0, d1, d2, d3;                                         \
                {   bf16x8 ah = *(const bf16x8*)&h1h[1 - (P)][l15][baseA];      \
                    bf16x8 al = *(const bf16x8*)&h1l[1 - (P)][l15][baseA];      \
                    d0 = MFMA16(ah, fr[0], zacc);  d0 = MFMA16(ah, fr[1], d0);  d0 = MFMA16(al, fr[0], d0);  \
                    d1 = MFMA16(ah, fr[8], zacc);  d1 = MFMA16(ah, fr[9], d1);  d1 = MFMA16(al, fr[8], d1);  \
                    d2 = MFMA16(ah, fr[16], zacc); d2 = MFMA16(ah, fr[17], d2); d2 = MFMA16(al, fr[16], d2); \
                    d3 = MFMA16(ah, fr[24], zacc); d3 = MFMA16(ah, fr[25], d3); d3 = MFMA16(al, fr[24], d3); \
                }                                                               \
                {   bf16x8 ah = *(const bf16x8*)&h1h[1 - (P)][l15][baseB];      \
                    bf16x8 al = *(const bf16x8*)&h1l[1 - (P)][l15][baseB];      \
                    d0 = MFMA16(ah, fr[2], d0);   d0 = MFMA16(ah, fr[3], d0);   d0 = MFMA16(al, fr[2], d0);  \
                    d1 = MFMA16(ah, fr[10], d1);  d1 = MFMA16(ah, fr[11], d1);  d1 = MFMA16(al, fr[10], d1); \
                    d2 = MFMA16(ah, fr[18], d2);  d2 = MFMA16(ah, fr[19], d2);  d2 = MFMA16(al, fr[18], d2); \
                    d3 = MFMA16(ah, fr[26], d3);  d3 = MFMA16(ah, fr[27], d3);  d3 = MFMA16(al, fr[26], d3); \
                }                                                               \
                {   bf16x8 ah = *(const bf16x8*)&h2h[(P)][l15][baseA];          \
                    bf16x8 al = *(const bf16x8*)&h2l[(P)][l15][baseA];          \
                    d0 = MFMA16(ah, fr[4], d0);   d0 = MFMA16(ah, fr[5], d0);   d0 = MFMA16(al, fr[4], d0);  \
                    d1 = MFMA16(ah, fr[12], d1);  d1 = MFMA16(ah, fr[13], d1);  d1 = MFMA16(al, fr[12], d1); \
                    d2 = MFMA16(ah, fr[20], d2);  d2 = MFMA16(ah, fr[21], d2);  d2 = MFMA16(al, fr[20], d2); \
                    d3 = MFMA16(ah, fr[28], d3);  d3 = MFMA16(ah, fr[29], d3);  d3 = MFMA16(al, fr[28], d3); \
                }                                                               \
                bf16x8 ah3 = *(const bf16x8*)&h2h[(P)][l15][baseB];             \
                bf16x8 al3 = *(const bf16x8*)&h2l[(P)][l15][baseB];             \
                floatx4 f0, f1, f2, f3;                                         \
                d0 = MFMA16(ah3, fr[6], d0);  d0 = MFMA16(ah3, fr[7], d0);  d0 = MFMA16(al3, fr[6], d0);  \
                GTAIL(d0, f0, -)                                                \
                d1 = MFMA16(ah3, fr[14], d1); d1 = MFMA16(ah3, fr[15], d1); d1 = MFMA16(al3, fr[14], d1); \
                GTAIL(d1, f1, -)                                                \
                d2 = MFMA16(ah3, fr[22], d2); d2 = MFMA16(ah3, fr[23], d2); d2 = MFMA16(al3, fr[22], d2); \
                GTAIL(d2, f2, +)                                                \
                d3 = MFMA16(ah3, fr[30], d3); d3 = MFMA16(ah3, fr[31], d3); d3 = MFMA16(al3, fr[30], d3); \
                GTAIL(d3, f3, -)                                                \
                _Pragma("unroll")                                               \
                for (int r = 0; r < 4; r++) {                                   \
                    float tgs = fmaf(-4.0f * L2E, f2[r], 2.0f * L2E);           \
                    float cn  = fmaf(f1[r], cst[r], f0[r] * tgs);               \
                    cst[r] = cn;                                                \
                    float th = fmaf(-2.0f, rcp_fast(1.0f + exp2_fast(cn)), 1.0f); \
                    float hv = f3[r] * th;                                      \
                    hv = uok ? hv : (uc == 51 ? 1.0f : 0.f);                    \
                    FIN_SPLIT(hv, h2h, h2l, 1 - (P));                           \
                }                                                               \
            }                                                                   \
        } else {                                                                \
            if ((IT) <= TT - 1) {                                               \
                float4 xn = {0.f, 0.f, 0.f, 0.f};                               \
                if (uc >= HH) xn = *(const float4*)&xb[((IT) + 1) * 16 + q * 4]; \
                floatx4 a0, a1, a2, a3;                                         \
                {   bf16x8 ah = *(const bf16x8*)&h1h[1 - (P)][l15][baseA];      \
                    bf16x8 al = *(const bf16x8*)&h1l[1 - (P)][l15][baseA];      \
                    a0 = MFMA16(ah, fr[0], zacc);  a0 = MFMA16(ah, fr[1], a0);  a0 = MFMA16(al, fr[0], a0);  \
                    a1 = MFMA16(ah, fr[4], zacc);  a1 = MFMA16(ah, fr[5], a1);  a1 = MFMA16(al, fr[4], a1);  \
                    a2 = MFMA16(ah, fr[8], zacc);  a2 = MFMA16(ah, fr[9], a2);  a2 = MFMA16(al, fr[8], a2);  \
                    a3 = MFMA16(ah, fr[12], zacc); a3 = MFMA16(ah, fr[13], a3); a3 = MFMA16(al, fr[12], a3); \
                }                                                               \
                bf16x8 ah1 = *(const bf16x8*)&h1h[1 - (P)][l15][baseB];         \
                bf16x8 al1 = *(const bf16x8*)&h1l[1 - (P)][l15][baseB];         \
                floatx4 f0, f1, f2, f3;                                         \
                a0 = MFMA16(ah1, fr[2], a0);  a0 = MFMA16(ah1, fr[3], a0);  a0 = MFMA16(al1, fr[2], a0);  \
                GTAIL(a0, f0, -)                                                \
                a1 = MFMA16(ah1, fr[6], a1);  a1 = MFMA16(ah1, fr[7], a1);  a1 = MFMA16(al1, fr[6], a1);  \
                GTAIL(a1, f1, -)                                                \
                a2 = MFMA16(ah1, fr[10], a2); a2 = MFMA16(ah1, fr[11], a2); a2 = MFMA16(al1, fr[10], a2); \
                GTAIL(a2, f2, +)                                                \
                a3 = MFMA16(ah1, fr[14], a3); a3 = MFMA16(ah1, fr[15], a3); a3 = MFMA16(al1, fr[14], a3); \
                GTAIL(a3, f3, -)                                                \
                _Pragma("unroll")                                               \
                for (int r = 0; r < 4; r++) {                                   \
                    float tgs = fmaf(-4.0f * L2E, f2[r], 2.0f * L2E);           \
                    float cn  = fmaf(f1[r], cst[r], f0[r] * tgs);               \
                    cst[r] = cn;                                                \
                    float th = fmaf(-2.0f, rcp_fast(1.0f + exp2_fast(cn)), 1.0f); \
                    float hv = f3[r] * th;                                      \
                    hv = uok ? hv : (uc == 51 ? 1.0f : (uc == 52 ? xn[r] : 0.f)); \
                    FIN_SPLIT(hv, h1h, h1l, (P));                               \
                }                                                               \
            }                                                                   \
            if ((IT) >= 2 && (w - 4) == ((IT) & 3)) {   /* rotated head */      \
                floatx4 ho;                                                     \
                {   bf16x8 ah = *(const bf16x8*)&h2h[(P)][l15][baseA];          \
                    bf16x8 al = *(const bf16x8*)&h2l[(P)][l15][baseA];          \
                    ho = MFMA16(ah, fr[16], zacc); ho = MFMA16(ah, fr[17], ho); ho = MFMA16(al, fr[16], ho); \
                }                                                               \
                {   bf16x8 ah = *(const bf16x8*)&h2h[(P)][l15][baseB];          \
                    bf16x8 al = *(const bf16x8*)&h2l[(P)][l15][baseB];          \
                    ho = MFMA16(ah, fr[18], ho);   ho = MFMA16(ah, fr[19], ho); ho = MFMA16(al, fr[18], ho); \
                }                                                               \
                if (l15 == 0) {                                                 \
                    _Pragma("unroll")                                           \
                    for (int r = 0; r < 4; r++)                                 \
                        out[(size_t)(b0g + q * 4 + r) * TT + ((IT) - 2)] = ho[r]; \
                }                                                               \
            }                                                                   \
        }                                                                       \
        __syncthreads();                                                        \
    } while (0)

    for (int itp = 0; itp < TT + 2; itp += 2) {
        STEP(itp, 0);
        STEP(itp + 1, 1);
    }
#undef STEP
#undef GTAIL
#undef FIN_SPLIT
}

extern "C" void kernel_launch(void* const* d_in, const int* in_sizes, int n_in,
                              void* d_out, int out_size, void* d_ws, size_t ws_size,
                              hipStream_t stream) {
    const float* input = (const float*)d_in[0];
    const float* Wih1  = (const float*)d_in[1];
    const float* Whh1  = (const float*)d_in[2];
    const float* bih1  = (const float*)d_in[3];
    const float* bhh1  = (const float*)d_in[4];
    const float* Wih2  = (const float*)d_in[5];
    const float* Whh2  = (const float*)d_in[6];
    const float* bih2  = (const float*)d_in[7];
    const float* bhh2  = (const float*)d_in[8];
    const float* Wlin  = (const float*)d_in[9];
    const float* blin  = (const float*)d_in[10];

    uint4* frags = (uint4*)d_ws;            // 196 frags * 1 KiB
    int B = in_sizes[0] / TT;               // 4096

    lstm_prep<<<49, 256, 0, stream>>>(Whh1, Wih1, bih1, bhh1, Wih2, Whh2,
                                      bih2, bhh2, Wlin, blin, frags);
    lstm_main<<<B / NB, 512, 0, stream>>>(input, frags, (float*)d_out);
}

// Round 10
// 377.156 us; speedup vs baseline: 1.0832x; 1.0832x over previous
//
#include <hip/hip_runtime.h>

#define HH 51
#define TT 256
#define NB 16
#define L2E 1.442695041f

typedef __attribute__((ext_vector_type(8))) _Float16 half8;
typedef __attribute__((ext_vector_type(4))) float   floatx4;

#define MFMA16F(A,B,C) __builtin_amdgcn_mfma_f32_16x16x32_f16((A),(B),(C),0,0,0)

__device__ __forceinline__ float rcp_fast(float x) { return __builtin_amdgcn_rcpf(x); }
#if __has_builtin(__builtin_amdgcn_exp2f)
__device__ __forceinline__ float exp2_fast(float x) { return __builtin_amdgcn_exp2f(x); }
#else
__device__ __forceinline__ float exp2_fast(float x) { return __expf(0.69314718056f * x); }
#endif
__device__ __forceinline__ unsigned short f2h_bits(float v) {
    return __builtin_bit_cast(unsigned short, (_Float16)v);
}

// ------------- weight pre-pack: fp16 hi/lo fragments, K-column folding ---
// B-frag 16x16x32_f16: lane holds B[k=(lane>>4)*8+jj][n=lane&15], 8 halves.
// ids: cell1 ((g*4+U)*2+s)*2+hl (64) | cell2 64+((g*4+U)*4+s)*2+hl (128) |
//      head 192+s*2+hl (4). ws = 196*64*16 B.
// K-columns: cell1 k<51=Whh1, k=51=bias1, k=52=Wih1 (x_hi), k=53=Wih1 (x_lo).
//            cell2 h1-half k<51=Wih2, k=51=bias2 (cols 52/53 ZERO so x passes
//            through harmlessly); h2-half k2<51=Whh2.
//            head n=0: k<51=Wlin, k=51=blin.
// Gate scales folded: i,f,o *L2E ; g *2*L2E ; head unscaled.
// hl=0 frag holds fp16(val); hl=1 holds fp16(val - fp16(val)).
__global__ void lstm_prep(const float* __restrict__ Whh1, const float* __restrict__ Wih1,
                          const float* __restrict__ bih1, const float* __restrict__ bhh1,
                          const float* __restrict__ Wih2, const float* __restrict__ Whh2,
                          const float* __restrict__ bih2, const float* __restrict__ bhh2,
                          const float* __restrict__ Wlin, const float* __restrict__ blin,
                          uint4* __restrict__ frags) {
    int tid = blockIdx.x * blockDim.x + threadIdx.x;
    if (tid >= 196 * 64) return;
    int f = tid >> 6, lane = tid & 63;
    int n = lane & 15, qq = lane >> 4;
    int hl, s, tau, cell;
    if (f < 64)       { cell = 1; int r = f;       hl = r & 1; r >>= 1; s = r & 1; tau = r >> 1; }
    else if (f < 192) { cell = 2; int r = f - 64;  hl = r & 1; r >>= 1; s = r & 3; tau = r >> 2; }
    else              { cell = 3; int r = f - 192; hl = r & 1; s = r >> 1; tau = 0; }
    int g = tau >> 2, U = tau & 3, u = U * 16 + n;
    float sc = (cell == 3) ? 1.0f : ((g == 2) ? 2.0f * L2E : L2E);
    unsigned int dw[4];
    for (int d = 0; d < 4; d++) {
        unsigned int packed = 0;
        for (int e = 0; e < 2; e++) {
            int jj = d * 2 + e;
            int k = s * 32 + qq * 8 + jj;
            float val = 0.f;
            if (cell == 1) {
                if (u < HH) {
                    if (k < HH)       val = Whh1[(g * HH + u) * HH + k];
                    else if (k == 51) val = bih1[g * HH + u] + bhh1[g * HH + u];
                    else              val = Wih1[g * HH + u];   // k=52,53
                }
            } else if (cell == 2) {
                if (u < HH) {
                    if (k < 64) {
                        if (k < HH)       val = Wih2[(g * HH + u) * HH + k];
                        else if (k == 51) val = bih2[g * HH + u] + bhh2[g * HH + u];
                        // k=52,53 stay 0 (x pass-through)
                    } else {
                        int k2 = k - 64;
                        if (k2 < HH) val = Whh2[(g * HH + u) * HH + k2];
                    }
                }
            } else {
                if (n == 0) {
                    if (k < HH)       val = Wlin[k];
                    else if (k == 51) val = blin[0];
                }
            }
            val *= sc;
            _Float16 hi = (_Float16)val;
            unsigned short bits;
            if (hl) { float lo = val - (float)hi; bits = f2h_bits(lo); }
            else    { bits = __builtin_bit_cast(unsigned short, hi); }
            packed |= ((unsigned int)bits) << (16 * e);
        }
        dw[d] = packed;
    }
    frags[f * 64 + lane] = make_uint4(dw[0], dw[1], dw[2], dw[3]);
}

// -------------------------------------------------------------------------
// One-barrier skewed LSTM (round-7/8 structure), fp16-h edition:
//  - h stored as SINGLE fp16 array (RNE cvt), weights hi/lo fp16
//    -> 2 MFMAs per k-step (was 3), LDS traffic halved
//  - zero-C MFMA init; bias/x/blin live in K-columns 51..53
//  - activation strictly AFTER all MFMAs (no peel - R9 regression reverted)
//  - head rotated across c1 waves ((w-4)==(IT&3))
// h layout: uint[2][16][36] (2 halves/uint), swizzle unchanged (verified):
//   write wi = (((u>>1)+4*(b>>1))&31)*2 + (u&1)  (half idx within row)
//   read  base = (ks*16 + q*4 + 4*(l15>>1)) & 31 (uint idx, b128)
// -------------------------------------------------------------------------
__launch_bounds__(512, 2)
__global__ void lstm_main(const float* __restrict__ input,
                          const uint4* __restrict__ frags,
                          float* __restrict__ out) {
    __shared__ __align__(16) unsigned int h1[2][16][36];
    __shared__ __align__(16) unsigned int h2[2][16][36];
    __shared__ __align__(16) float xb[(TT + 1) * 16];    // [t][b], row TT = 0

    const int tid  = threadIdx.x;
    const int lane = tid & 63;
    const int w    = tid >> 6;
    const int l15  = lane & 15;
    const int q    = lane >> 4;
    const int b0g  = blockIdx.x * NB;
    const bool c2w = (w < 4);
    const int U    = c2w ? w : (w - 4);
    const int uc   = U * 16 + l15;
    const bool uok = (uc < HH);

    for (int i = tid; i < 2 * 16 * 36; i += 512) {
        ((unsigned*)h1)[i] = 0; ((unsigned*)h2)[i] = 0;
    }
    for (int c = 0; c < 2; c++) {
        int flat = tid + c * 512;
        int b = flat >> 6, t0 = (flat & 63) * 4;
        float4 v = *(const float4*)&input[(size_t)(b0g + b) * TT + t0];
        xb[(t0 + 0) * 16 + b] = v.x; xb[(t0 + 1) * 16 + b] = v.y;
        xb[(t0 + 2) * 16 + b] = v.z; xb[(t0 + 3) * 16 + b] = v.w;
    }
    if (tid < 16) xb[TT * 16 + tid] = 0.f;
    __syncthreads();
    if (tid < 16) {                         // initial hooks in h1 parity 1
        int b = tid;
        int wi51 = ((25 + 4 * (b >> 1)) & 31) * 2 + 1;   // u=51 (bias col)
        int wi52 = ((26 + 4 * (b >> 1)) & 31) * 2 + 0;   // u=52 (x_hi)
        int wi53 = ((26 + 4 * (b >> 1)) & 31) * 2 + 1;   // u=53 (x_lo)
        ((unsigned short*)&h1[1][b][0])[wi51] = 0x3C00;  // fp16(1.0)
        float x0 = input[(size_t)(b0g + b) * TT];
        _Float16 xh = (_Float16)x0;
        ((unsigned short*)&h1[1][b][0])[wi52] = __builtin_bit_cast(unsigned short, xh);
        ((unsigned short*)&h1[1][b][0])[wi53] = f2h_bits(x0 - (float)xh);
    }

    // weight-stationary fragments
    half8 fr[32];
    if (c2w) {
#pragma unroll
        for (int g = 0; g < 4; g++) {
            int tau = g * 4 + U;
#pragma unroll
            for (int s = 0; s < 4; s++) {
                fr[g * 8 + s * 2 + 0] = __builtin_bit_cast(half8, frags[(64 + (tau * 4 + s) * 2 + 0) * 64 + lane]);
                fr[g * 8 + s * 2 + 1] = __builtin_bit_cast(half8, frags[(64 + (tau * 4 + s) * 2 + 1) * 64 + lane]);
            }
        }
    } else {
#pragma unroll
        for (int g = 0; g < 4; g++) {
            int tau = g * 4 + U;
#pragma unroll
            for (int s = 0; s < 2; s++) {
                fr[g * 4 + s * 2 + 0] = __builtin_bit_cast(half8, frags[((tau * 2 + s) * 2 + 0) * 64 + lane]);
                fr[g * 4 + s * 2 + 1] = __builtin_bit_cast(half8, frags[((tau * 2 + s) * 2 + 1) * 64 + lane]);
            }
        }
#pragma unroll
        for (int s = 0; s < 2; s++) {       // head frags on ALL c1 waves
            fr[16 + s * 2 + 0] = __builtin_bit_cast(half8, frags[(192 + s * 2 + 0) * 64 + lane]);
            fr[16 + s * 2 + 1] = __builtin_bit_cast(half8, frags[(192 + s * 2 + 1) * 64 + lane]);
        }
    }
    floatx4 zacc = {0.f, 0.f, 0.f, 0.f};
    float cst[4] = {0.f, 0.f, 0.f, 0.f};
    const int baseA = (q * 4 + 4 * (l15 >> 1)) & 31;
    const int baseB = (baseA + 16) & 31;

    __syncthreads();

#define GTAIL(DG, FG, SGN)                                                      \
    _Pragma("unroll")                                                           \
    for (int r = 0; r < 4; r++) {                                               \
        float e = exp2_fast(SGN (DG)[r]);                                       \
        (FG)[r] = rcp_fast(1.0f + e);                                           \
    }

#define STEP(IT, P)                                                             \
    do {                                                                        \
        if (c2w) {                                                              \
            if ((IT) >= 1 && (IT) <= TT) {       /* cell2 -> h2(IT-1) */        \
                half8 a0 = *(const half8*)&h1[1 - (P)][l15][baseA];             \
                half8 a1 = *(const half8*)&h1[1 - (P)][l15][baseB];             \
                half8 a2 = *(const half8*)&h2[(P)][l15][baseA];                 \
                half8 a3 = *(const half8*)&h2[(P)][l15][baseB];                 \
                floatx4 d0, d1, d2, d3;                                         \
                d0 = MFMA16F(a0, fr[0],  zacc); d0 = MFMA16F(a0, fr[1],  d0);   \
                d1 = MFMA16F(a0, fr[8],  zacc); d1 = MFMA16F(a0, fr[9],  d1);   \
                d2 = MFMA16F(a0, fr[16], zacc); d2 = MFMA16F(a0, fr[17], d2);   \
                d3 = MFMA16F(a0, fr[24], zacc); d3 = MFMA16F(a0, fr[25], d3);   \
                d0 = MFMA16F(a1, fr[2],  d0);   d0 = MFMA16F(a1, fr[3],  d0);   \
                d1 = MFMA16F(a1, fr[10], d1);   d1 = MFMA16F(a1, fr[11], d1);   \
                d2 = MFMA16F(a1, fr[18], d2);   d2 = MFMA16F(a1, fr[19], d2);   \
                d3 = MFMA16F(a1, fr[26], d3);   d3 = MFMA16F(a1, fr[27], d3);   \
                d0 = MFMA16F(a2, fr[4],  d0);   d0 = MFMA16F(a2, fr[5],  d0);   \
                d1 = MFMA16F(a2, fr[12], d1);   d1 = MFMA16F(a2, fr[13], d1);   \
                d2 = MFMA16F(a2, fr[20], d2);   d2 = MFMA16F(a2, fr[21], d2);   \
                d3 = MFMA16F(a2, fr[28], d3);   d3 = MFMA16F(a2, fr[29], d3);   \
                d0 = MFMA16F(a3, fr[6],  d0);   d0 = MFMA16F(a3, fr[7],  d0);   \
                d1 = MFMA16F(a3, fr[14], d1);   d1 = MFMA16F(a3, fr[15], d1);   \
                d2 = MFMA16F(a3, fr[22], d2);   d2 = MFMA16F(a3, fr[23], d2);   \
                d3 = MFMA16F(a3, fr[30], d3);   d3 = MFMA16F(a3, fr[31], d3);   \
                floatx4 f0, f1, f2, f3;                                         \
                GTAIL(d0, f0, -) GTAIL(d1, f1, -) GTAIL(d2, f2, +) GTAIL(d3, f3, -) \
                _Pragma("unroll")                                               \
                for (int r = 0; r < 4; r++) {                                   \
                    float tgs = fmaf(-4.0f * L2E, f2[r], 2.0f * L2E);           \
                    float cn  = fmaf(f1[r], cst[r], f0[r] * tgs);               \
                    cst[r] = cn;                                                \
                    float th = fmaf(-2.0f, rcp_fast(1.0f + exp2_fast(cn)), 1.0f); \
                    float hv = f3[r] * th;                                      \
                    hv = uok ? hv : (uc == 51 ? 1.0f : 0.f);                    \
                    int bb = q * 4 + r;                                         \
                    int wi = (((uc >> 1) + 4 * (bb >> 1)) & 31) * 2 + (uc & 1); \
                    ((unsigned short*)&h2[1 - (P)][bb][0])[wi] = f2h_bits(hv);  \
                }                                                               \
            }                                                                   \
        } else {                                                                \
            if ((IT) <= TT - 1) {                /* cell1 -> h1(IT) */          \
                float4 xn = {0.f, 0.f, 0.f, 0.f};                               \
                if (uc >= HH) xn = *(const float4*)&xb[((IT) + 1) * 16 + q * 4]; \
                half8 a0 = *(const half8*)&h1[1 - (P)][l15][baseA];             \
                half8 a1 = *(const half8*)&h1[1 - (P)][l15][baseB];             \
                floatx4 d0, d1, d2, d3;                                         \
                d0 = MFMA16F(a0, fr[0],  zacc); d0 = MFMA16F(a0, fr[1],  d0);   \
                d1 = MFMA16F(a0, fr[4],  zacc); d1 = MFMA16F(a0, fr[5],  d1);   \
                d2 = MFMA16F(a0, fr[8],  zacc); d2 = MFMA16F(a0, fr[9],  d2);   \
                d3 = MFMA16F(a0, fr[12], zacc); d3 = MFMA16F(a0, fr[13], d3);   \
                d0 = MFMA16F(a1, fr[2],  d0);   d0 = MFMA16F(a1, fr[3],  d0);   \
                d1 = MFMA16F(a1, fr[6],  d1);   d1 = MFMA16F(a1, fr[7],  d1);   \
                d2 = MFMA16F(a1, fr[10], d2);   d2 = MFMA16F(a1, fr[11], d2);   \
                d3 = MFMA16F(a1, fr[14], d3);   d3 = MFMA16F(a1, fr[15], d3);   \
                floatx4 f0, f1, f2, f3;                                         \
                GTAIL(d0, f0, -) GTAIL(d1, f1, -) GTAIL(d2, f2, +) GTAIL(d3, f3, -) \
                _Pragma("unroll")                                               \
                for (int r = 0; r < 4; r++) {                                   \
                    float tgs = fmaf(-4.0f * L2E, f2[r], 2.0f * L2E);           \
                    float cn  = fmaf(f1[r], cst[r], f0[r] * tgs);               \
                    cst[r] = cn;                                                \
                    float th = fmaf(-2.0f, rcp_fast(1.0f + exp2_fast(cn)), 1.0f); \
                    float hv = f3[r] * th;                                      \
                    hv = uok ? hv                                               \
                             : (uc == 51 ? 1.0f                                 \
                             : (uc == 52 ? xn[r]                                \
                             : (uc == 53 ? xn[r] - (float)(_Float16)xn[r] : 0.f))); \
                    int bb = q * 4 + r;                                         \
                    int wi = (((uc >> 1) + 4 * (bb >> 1)) & 31) * 2 + (uc & 1); \
                    ((unsigned short*)&h1[(P)][bb][0])[wi] = f2h_bits(hv);      \
                }                                                               \
            }                                                                   \
            if ((IT) >= 2 && (w - 4) == ((IT) & 3)) {   /* rotated head */      \
                half8 a2 = *(const half8*)&h2[(P)][l15][baseA];                 \
                half8 a3 = *(const half8*)&h2[(P)][l15][baseB];                 \
                floatx4 ho;                                                     \
                ho = MFMA16F(a2, fr[16], zacc); ho = MFMA16F(a2, fr[17], ho);   \
                ho = MFMA16F(a3, fr[18], ho);   ho = MFMA16F(a3, fr[19], ho);   \
                if (l15 == 0) {                                                 \
                    _Pragma("unroll")                                           \
                    for (int r = 0; r < 4; r++)                                 \
                        out[(size_t)(b0g + q * 4 + r) * TT + ((IT) - 2)] = ho[r]; \
                }                                                               \
            }                                                                   \
        }                                                                       \
        __syncthreads();                                                        \
    } while (0)

    for (int itp = 0; itp < TT + 2; itp += 2) {
        STEP(itp, 0);
        STEP(itp + 1, 1);
    }
#undef STEP
#undef GTAIL
}

extern "C" void kernel_launch(void* const* d_in, const int* in_sizes, int n_in,
                              void* d_out, int out_size, void* d_ws, size_t ws_size,
                              hipStream_t stream) {
    const float* input = (const float*)d_in[0];
    const float* Wih1  = (const float*)d_in[1];
    const float* Whh1  = (const float*)d_in[2];
    const float* bih1  = (const float*)d_in[3];
    const float* bhh1  = (const float*)d_in[4];
    const float* Wih2  = (const float*)d_in[5];
    const float* Whh2  = (const float*)d_in[6];
    const float* bih2  = (const float*)d_in[7];
    const float* bhh2  = (const float*)d_in[8];
    const float* Wlin  = (const float*)d_in[9];
    const float* blin  = (const float*)d_in[10];

    uint4* frags = (uint4*)d_ws;            // 196 frags * 1 KiB
    int B = in_sizes[0] / TT;               // 4096

    lstm_prep<<<49, 256, 0, stream>>>(Whh1, Wih1, bih1, bhh1, Wih2, Whh2,
                                      bih2, bhh2, Wlin, blin, frags);
    lstm_main<<<B / NB, 512, 0, stream>>>(input, frags, (float*)d_out);
}